// Round 2
// baseline (254.675 us; speedup 1.0000x reference)
//
#include <hip/hip_runtime.h>
#include <math.h>

#define BB 32
#define PP 2048
#define CC 512
#define TT 128            // PP/16
#define NROWS (BB*PP)     // 65536
#define NTILES (BB*TT)    // 4096 (b,t) tiles, 16 rows x 512 ch each

// K1: channel-mean of each of 65536 rows. One block per (b,t) tile (16 rows,
// 32 KB). Each thread reads 8 float4 into 8 INDEPENDENT accumulators (deep
// MLP, no hold), then hierarchical wave-shuffle + LDS reduce.
// Element e = tid + 256*j  ->  row (tid>>7) + 2*j, so waves 0,1 own even
// rows and waves 2,3 own odd rows.
__global__ __launch_bounds__(256) void mean_kernel(
        const float* __restrict__ x, float* __restrict__ mean) {
    __shared__ float spart[4][8];
    int bid  = blockIdx.x;
    int tid  = threadIdx.x;
    int wave = tid >> 6;
    int lane = tid & 63;

    const float4* xt = (const float4*)x + (size_t)bid * 2048;
    float p[8];
    #pragma unroll
    for (int j = 0; j < 8; ++j) {
        float4 v = xt[tid + 256 * j];
        p[j] = (v.x + v.y) + (v.z + v.w);
    }
    #pragma unroll
    for (int j = 0; j < 8; ++j) {
        float s = p[j];
        #pragma unroll
        for (int off = 32; off > 0; off >>= 1)
            s += __shfl_down(s, off, 64);
        if (lane == 0) spart[wave][j] = s;
    }
    __syncthreads();
    if (tid < 16) {
        int jj = tid >> 1;
        float s = (tid & 1) ? (spart[2][jj] + spart[3][jj])
                            : (spart[0][jj] + spart[1][jj]);
        mean[bid * 16 + tid] = s * (1.0f / 512.0f);
    }
}

// K2: per-tile gate (27-tap combined stencil on cached means) + streaming
// scale. Prologue reads 48 means (L2-hot) and computes 16 gates; main loop
// is a pure load->mul->store stream with 8 independent float4 pairs/thread.
__global__ __launch_bounds__(256) void gate_scale_kernel(
        const float* __restrict__ x, const float* __restrict__ mean,
        const float* __restrict__ w1, const float* __restrict__ w2,
        const float* __restrict__ w3, float* __restrict__ out) {
    __shared__ float sm[3][16];     // planes t-1 / t / t+1
    __shared__ float sgate[16];
    int bid = blockIdx.x;
    int b = bid >> 7;
    int t = bid & 127;
    int tid = threadIdx.x;

    if (tid < 48) {
        int plane = tid >> 4;       // 0,1,2 -> t-1, t, t+1
        int r     = tid & 15;
        int tv    = t + plane - 1;
        sm[plane][r] = (tv >= 0 && tv < TT)
                         ? mean[(b * TT + tv) * 16 + r] : 0.0f;
    }
    __syncthreads();

    if (tid < 16) {
        int h  = tid >> 2;
        int w_ = tid & 3;
        float g = 0.0f;
        #pragma unroll
        for (int i = 0; i < 3; ++i) {
            #pragma unroll
            for (int j = 0; j < 3; ++j) {
                int hh = h + j - 1;
                if (hh < 0 || hh > 3) continue;
                #pragma unroll
                for (int k = 0; k < 3; ++k) {
                    int ww = w_ + k - 1;
                    if (ww < 0 || ww > 3) continue;
                    float wt = w3[i * 9 + j * 3 + k];
                    if (i < 2 && j < 2 && k < 2) wt += w2[i * 4 + j * 2 + k];
                    if (i == 1 && j == 1 && k == 1) wt += w1[0];
                    g += wt * sm[i][hh * 4 + ww];
                }
            }
        }
        sgate[tid] = 1.0f / (1.0f + __expf(-g));
    }
    __syncthreads();

    const float4* xt = (const float4*)x + (size_t)bid * 2048;
    float4*       ot = (float4*)out     + (size_t)bid * 2048;
    #pragma unroll
    for (int j = 0; j < 8; ++j) {
        int idx = tid + 256 * j;
        float s = sgate[idx >> 7];
        float4 v = xt[idx];
        v.x *= s; v.y *= s; v.z *= s; v.w *= s;
        ot[idx] = v;
    }
}

extern "C" void kernel_launch(void* const* d_in, const int* in_sizes, int n_in,
                              void* d_out, int out_size, void* d_ws, size_t ws_size,
                              hipStream_t stream) {
    const float* x  = (const float*)d_in[0];
    const float* w1 = (const float*)d_in[1];
    const float* w2 = (const float*)d_in[2];
    const float* w3 = (const float*)d_in[3];
    float* out  = (float*)d_out;
    float* mean = (float*)d_ws;            // 65536 floats

    mean_kernel<<<NTILES, 256, 0, stream>>>(x, mean);
    gate_scale_kernel<<<NTILES, 256, 0, stream>>>(x, mean, w1, w2, w3, out);
}

// Round 3
// 245.176 us; speedup vs baseline: 1.0387x; 1.0387x over previous
//
#include <hip/hip_runtime.h>
#include <math.h>

#define BB 32
#define PP 2048
#define CC 512
#define TT 128            // PP/16
#define NCHUNK 64         // TT/2: two t-planes per block
#define NBLK (BB*NCHUNK)  // 2048 blocks

// Fused mean + 27-tap gate + sigmoid + scale, one block per (b, t-pair).
// Block owns planes t0,t0+1 (16 rows x 512 ch each) held in registers;
// halo planes t0-1 and t0+2 are read once (each plane is halo for exactly
// one neighbor chunk -> 2x total read amplification vs r1's 3x).
// Thread layout: tid -> row = tid>>4 (0..15), seg = tid&15. Row mean is
// 8 in-thread adds + one 4-step shfl_xor tree (shallow critical path).
__global__ __launch_bounds__(256, 4) void fused2_kernel(
        const float* __restrict__ x,
        const float* __restrict__ w1, const float* __restrict__ w2,
        const float* __restrict__ w3, float* __restrict__ out) {
    __shared__ float sm[4][16];   // planes t0-1, t0, t0+1, t0+2
    __shared__ float sg[32];      // gates for planes t0, t0+1

    // XCD-chunked swizzle: 2048 blocks = 8 XCDs x 256. Neighbor chunks
    // (which share halo planes) land on the same XCD -> halo L2 hits.
    int bid = blockIdx.x;
    int wg  = ((bid & 7) << 8) | (bid >> 3);
    int b  = wg >> 6;             // /64
    int c  = wg & 63;
    int t0 = c << 1;

    int tid = threadIdx.x;
    int row = tid >> 4;           // 0..15 spatial row within plane
    int seg = tid & 15;           // 16 float4-columns apart

    const float4* xb = (const float4*)x + (size_t)b * (PP * CC / 4);
    const float4* xp0 = xb + (size_t)t0 * 2048;
    const float4* xp1 = xp0 + 2048;

    // ---- own planes: 16 float4/thread held in registers ----
    float4 v0[8], v1[8];
    #pragma unroll
    for (int k = 0; k < 8; ++k) v0[k] = xp0[row * 128 + seg + 16 * k];
    #pragma unroll
    for (int k = 0; k < 8; ++k) v1[k] = xp1[row * 128 + seg + 16 * k];

    // ---- halo planes t0-1, t0+2: 32 rows, 8 threads/row, 16 f4/thread ----
    int hr     = tid >> 3;        // 0..31
    int hu     = tid & 7;
    int hplane = hr >> 4;         // 0 -> t0-1, 1 -> t0+2
    int hrow   = hr & 15;
    int ht     = hplane ? (t0 + 2) : (t0 - 1);
    bool hv    = (ht >= 0) && (ht < TT);
    float ha = 0.0f, hb2 = 0.0f;  // two independent accumulator chains
    if (hv) {
        const float4* hp = xb + (size_t)ht * 2048 + hrow * 128;
        #pragma unroll
        for (int k = 0; k < 8; ++k) {
            float4 u = hp[hu + 8 * (2 * k)];
            float4 w = hp[hu + 8 * (2 * k + 1)];
            ha  += (u.x + u.y) + (u.z + u.w);
            hb2 += (w.x + w.y) + (w.z + w.w);
        }
    }
    float hs = ha + hb2;
    hs += __shfl_xor(hs, 1, 64);
    hs += __shfl_xor(hs, 2, 64);
    hs += __shfl_xor(hs, 4, 64);

    // ---- own-row sums: one shallow tree per plane ----
    float s0 = 0.0f, s1 = 0.0f;
    #pragma unroll
    for (int k = 0; k < 8; ++k) s0 += (v0[k].x + v0[k].y) + (v0[k].z + v0[k].w);
    #pragma unroll
    for (int k = 0; k < 8; ++k) s1 += (v1[k].x + v1[k].y) + (v1[k].z + v1[k].w);
    #pragma unroll
    for (int m = 1; m <= 8; m <<= 1) {
        s0 += __shfl_xor(s0, m, 64);
        s1 += __shfl_xor(s1, m, 64);
    }

    if (seg == 0) {
        sm[1][row] = s0 * (1.0f / 512.0f);
        sm[2][row] = s1 * (1.0f / 512.0f);
    }
    if (hu == 0) sm[hplane ? 3 : 0][hrow] = hv ? hs * (1.0f / 512.0f) : 0.0f;
    __syncthreads();

    // ---- 32 gates: plane q = tid>>4, position r = tid&15 ----
    if (tid < 32) {
        int q  = tid >> 4;
        int r  = tid & 15;
        int h  = r >> 2;
        int w_ = r & 3;
        float g = 0.0f;
        #pragma unroll
        for (int i = 0; i < 3; ++i) {
            #pragma unroll
            for (int j = 0; j < 3; ++j) {
                int hh = h + j - 1;
                if (hh < 0 || hh > 3) continue;
                #pragma unroll
                for (int k = 0; k < 3; ++k) {
                    int ww = w_ + k - 1;
                    if (ww < 0 || ww > 3) continue;
                    float wt = w3[i * 9 + j * 3 + k];
                    if (i < 2 && j < 2 && k < 2) wt += w2[i * 4 + j * 2 + k];
                    if (i == 1 && j == 1 && k == 1) wt += w1[0];
                    g += wt * sm[q + i][hh * 4 + ww];   // sm[q+i] = plane t0+q+i-1
                }
            }
        }
        sg[tid] = 1.0f / (1.0f + __expf(-g));
    }
    __syncthreads();

    // ---- scale held registers, coalesced store ----
    float g0 = sg[row];
    float g1 = sg[16 + row];
    float4* ob = (float4*)out + (size_t)b * (PP * CC / 4) + (size_t)t0 * 2048;
    #pragma unroll
    for (int k = 0; k < 8; ++k) {
        float4 o = v0[k];
        o.x *= g0; o.y *= g0; o.z *= g0; o.w *= g0;
        ob[row * 128 + seg + 16 * k] = o;
    }
    #pragma unroll
    for (int k = 0; k < 8; ++k) {
        float4 o = v1[k];
        o.x *= g1; o.y *= g1; o.z *= g1; o.w *= g1;
        ob[2048 + row * 128 + seg + 16 * k] = o;
    }
}

extern "C" void kernel_launch(void* const* d_in, const int* in_sizes, int n_in,
                              void* d_out, int out_size, void* d_ws, size_t ws_size,
                              hipStream_t stream) {
    const float* x  = (const float*)d_in[0];
    const float* w1 = (const float*)d_in[1];
    const float* w2 = (const float*)d_in[2];
    const float* w3 = (const float*)d_in[3];
    float* out = (float*)d_out;

    fused2_kernel<<<NBLK, 256, 0, stream>>>(x, w1, w2, w3, out);
}